// Round 1
// 390.760 us; speedup vs baseline: 1.0142x; 1.0142x over previous
//
#include <hip/hip_runtime.h>

// CostVolume: out[b,c,h,x,d] = (x>=d) ? left[b,c,h,x] - right[b,c,h,x-d] : 0
// B=4, C=32, H=128, W=240, D=24 (fp32 in/out). Write-bound: 377.5 MB out,
// 31.5 MB in -> ~65-70 us floor at 6.3 TB/s achievable.
//
// R2 change: 8 rows per block (was 1). 8*1440 = 11520 float4 = exactly 45
// tail-free iterations of 256 threads: one barrier per 8 rows (was 1/row),
// contiguous 7.68 KB staging loads, 45 independent full-width stores per
// thread, 2048 blocks (8/CU, 32 waves/CU, 122.9 KB LDS/CU).
// Flat trick: pg = q/6 is simultaneously the LDS index for left AND the base
// for the shifted right read (pg - d), since rows are laid out flat in LDS.

constexpr int W_IMG     = 240;
constexpr int D_LEV     = 24;
constexpr int ROWS_PB   = 8;                               // rows per block
constexpr int FLOATS_PB = ROWS_PB * W_IMG;                 // 1920 floats/image
constexpr int F4_STAGE  = FLOATS_PB / 4;                   // 480 float4 stages
constexpr int Q_PER_BLK = ROWS_PB * W_IMG * D_LEV / 4;     // 11520 float4 out
constexpr int ITERS     = Q_PER_BLK / 256;                 // 45, exact

__global__ __launch_bounds__(256) void cost_volume_kernel(
    const float4* __restrict__ left4,
    const float4* __restrict__ right4,
    float4* __restrict__ out4)
{
    __shared__ float lrow[FLOATS_PB];
    __shared__ float rrow[FLOATS_PB];

    const int t = threadIdx.x;
    const long long blk = blockIdx.x;
    const int sbase = (int)blk * F4_STAGE;     // <= 2047*480, fits int

    // Stage 8 left rows + 8 right rows: each a contiguous 7.68 KB block,
    // fully coalesced float4 loads (480 per image, 256 threads -> 2 iters).
    for (int s = t; s < F4_STAGE; s += 256)
        ((float4*)lrow)[s] = left4[sbase + s];
    for (int s = t; s < F4_STAGE; s += 256)
        ((float4*)rrow)[s] = right4[sbase + s];
    __syncthreads();

    float4* __restrict__ out_blk = out4 + blk * Q_PER_BLK;

    #pragma unroll 5
    for (int it = 0; it < ITERS; ++it) {
        const int q   = t + it * 256;      // 0 .. 11519, no tail
        const int pg  = q / 6;             // flat pixel index 0 .. 1919 (magic-mul)
        const int j   = q - pg * 6;        // float4 group within pixel: d = 4j+k
        const int pix = pg % 240;          // column within row (magic-mul)
        const int d0  = 4 * j;

        const float lv = lrow[pg];
        const int f = pg - d0;             // flat right index for k=0
        const int c = pix - d0;            // validity: need c >= k

        // Masked lanes read clamped (harmless) addresses; result forced to 0.
        float4 o;
        { int fi = f;     float r = rrow[fi > 0 ? fi : 0]; o.x = (c >= 0) ? lv - r : 0.0f; }
        { int fi = f - 1; float r = rrow[fi > 0 ? fi : 0]; o.y = (c >= 1) ? lv - r : 0.0f; }
        { int fi = f - 2; float r = rrow[fi > 0 ? fi : 0]; o.z = (c >= 2) ? lv - r : 0.0f; }
        { int fi = f - 3; float r = rrow[fi > 0 ? fi : 0]; o.w = (c >= 3) ? lv - r : 0.0f; }

        out_blk[q] = o;                    // wave: 1 KB contiguous; block: 180 KB contiguous
    }
}

extern "C" void kernel_launch(void* const* d_in, const int* in_sizes, int n_in,
                              void* d_out, int out_size, void* d_ws, size_t ws_size,
                              hipStream_t stream) {
    const float* left  = (const float*)d_in[0];
    const float* right = (const float*)d_in[1];
    float*       out   = (float*)d_out;

    const int n_pix  = in_sizes[0];            // B*C*H*W
    const int rows   = n_pix / W_IMG;          // 16384
    const int blocks = rows / ROWS_PB;         // 2048

    cost_volume_kernel<<<blocks, 256, 0, stream>>>(
        (const float4*)left, (const float4*)right, (float4*)out);
}